// Round 14
// baseline (698.387 us; speedup 1.0000x reference)
//
#include <hip/hip_runtime.h>
#include <hip/hip_bf16.h>
#include <cstdint>
#include <cstddef>

#define BS 2
#define SLEN 4096
#define DIM 2048
#define INNER 1024
#define NEXP 16
#define CAP 512
#define TPE (BS*CAP)      // 1024 tokens per expert
#define NTOK (BS*SLEN)    // 8192

typedef __attribute__((ext_vector_type(4))) float f32x4;
typedef __attribute__((ext_vector_type(8))) short s16x8;

static __device__ __forceinline__ unsigned short f2bf(float f){
  unsigned u = __float_as_uint(f);
  u += 0x7FFFu + ((u >> 16) & 1u);   // RNE
  return (unsigned short)(u >> 16);
}
static __device__ __forceinline__ float bf2f(unsigned short u){
  return __uint_as_float(((unsigned)u) << 16);
}
static __device__ __forceinline__ float sigmoidf_(float x){ return 1.0f/(1.0f+expf(-x)); }

static __device__ __forceinline__ void gload16(const unsigned short* g, short* l){
  __builtin_amdgcn_global_load_lds(
      (const __attribute__((address_space(1))) void*)g,
      (__attribute__((address_space(3))) void*)l, 16, 0, 0);
}

// ---------------- cast fp32 -> bf16 (vectorized) ----------------
__global__ __launch_bounds__(256) void cast_kernel(const float* __restrict__ in,
    unsigned short* __restrict__ out, long n){
  long i = ((long)blockIdx.x*256 + threadIdx.x)*8;
  if (i >= n) return;
  f32x4 a = *reinterpret_cast<const f32x4*>(in+i);
  f32x4 b = *reinterpret_cast<const f32x4*>(in+i+4);
  s16x8 o;
  o[0]=(short)f2bf(a[0]); o[1]=(short)f2bf(a[1]); o[2]=(short)f2bf(a[2]); o[3]=(short)f2bf(a[3]);
  o[4]=(short)f2bf(b[0]); o[5]=(short)f2bf(b[1]); o[6]=(short)f2bf(b[2]); o[7]=(short)f2bf(b[3]);
  *reinterpret_cast<s16x8*>(out+i) = o;
}

// ------------- transpose + cast v2: 64x64 tiles, vectorized both sides -------------
__global__ __launch_bounds__(256) void transpose_cast_kernel(const float* __restrict__ in,
    unsigned short* __restrict__ out, int R, int C){
  __shared__ float t[64][65];
  const size_t mat = blockIdx.z;
  const float* src = in + mat*(size_t)R*C;
  unsigned short* dst = out + mat*(size_t)R*C;
  const int c0 = blockIdx.x*64, r0 = blockIdx.y*64;
  const int tid = threadIdx.x;
  const int tr = tid >> 4, tc4 = (tid & 15)*4;
  #pragma unroll
  for (int i=0;i<4;i++){
    f32x4 v = *reinterpret_cast<const f32x4*>(src + (size_t)(r0+tr+16*i)*C + c0 + tc4);
    t[tr+16*i][tc4+0]=v[0]; t[tr+16*i][tc4+1]=v[1]; t[tr+16*i][tc4+2]=v[2]; t[tr+16*i][tc4+3]=v[3];
  }
  __syncthreads();
  const int sc = tid >> 3, srs = (tid & 7)*8;
  #pragma unroll
  for (int i=0;i<2;i++){
    int cc = sc + 32*i;
    s16x8 o;
    #pragma unroll
    for (int j=0;j<8;j++) o[j] = (short)f2bf(t[srs+j][cc]);
    *reinterpret_cast<s16x8*>(dst + (size_t)(c0+cc)*R + r0 + srs) = o;
  }
}

// ---------------- timestep part of router logits: tpart[b][e] ----------------
__global__ __launch_bounds__(256) void tpart_kernel(const float* __restrict__ timestep,
    const float* __restrict__ gate_w, float* __restrict__ tpart){
  int b = blockIdx.x >> 4, e = blockIdx.x & 15;
  float acc = 0.f;
  for (int d = threadIdx.x; d < DIM; d += 256)
    acc += timestep[b*DIM + d] * gate_w[(size_t)d*NEXP + e];
  #pragma unroll
  for (int o=32;o>0;o>>=1) acc += __shfl_down(acc, o);
  __shared__ float red[4];
  int lane = threadIdx.x & 63, wid = threadIdx.x >> 6;
  if (lane==0) red[wid] = acc;
  __syncthreads();
  if (threadIdx.x==0) tpart[blockIdx.x] = red[0]+red[1]+red[2]+red[3];
}

// ------- router v3: native gate_w[k][e] layout -> one 64B broadcast line per k -------
__global__ __launch_bounds__(256) void router3_kernel(const float* __restrict__ xu,
    const float* __restrict__ gate_w, const float* __restrict__ tpart,
    float* __restrict__ scores, float* __restrict__ token_sums, int* __restrict__ hit_cnt){
  const int tid = threadIdx.x;
  if (tid < 16){
    int tt = blockIdx.x*16 + tid;
    token_sums[tt] = 0.f;
    hit_cnt[tt] = 0;
  }
  const int lane = tid & 63, wv = tid >> 6;
  const int tsub = lane >> 4, e = lane & 15;
  const int tok = blockIdx.x*16 + wv*4 + tsub;
  const int b = tok >> 12, s = tok & (SLEN-1);
  const float* xr  = xu + (size_t)tok*DIM;
  const float* gw2 = gate_w + (size_t)DIM*NEXP + e;   // second-half rows, expert e
  float a0=0.f, a1=0.f;
  #pragma unroll 4
  for (int k = 0; k < DIM; k += 8){
    f32x4 x0 = *reinterpret_cast<const f32x4*>(xr+k);
    f32x4 x1 = *reinterpret_cast<const f32x4*>(xr+k+4);
    a0 += x0[0]*gw2[(size_t)(k+0)*NEXP] + x0[1]*gw2[(size_t)(k+1)*NEXP]
        + x0[2]*gw2[(size_t)(k+2)*NEXP] + x0[3]*gw2[(size_t)(k+3)*NEXP];
    a1 += x1[0]*gw2[(size_t)(k+4)*NEXP] + x1[1]*gw2[(size_t)(k+5)*NEXP]
        + x1[2]*gw2[(size_t)(k+6)*NEXP] + x1[3]*gw2[(size_t)(k+7)*NEXP];
  }
  float v = a0 + a1 + tpart[b*NEXP+e];
  scores[((size_t)(b*NEXP+e))*SLEN + s] = sigmoidf_(v);
}

// ------------- top-512 per (b,e) via exact radix-select + inverse hit index -------------
__global__ __launch_bounds__(1024) void topk_kernel(const float* __restrict__ scores,
    int* __restrict__ tok_idx, float* __restrict__ gate_raw, float* __restrict__ token_sums,
    int* __restrict__ hit_cnt, int* __restrict__ hit_slot){
  __shared__ unsigned keys[SLEN];
  __shared__ unsigned hist[256];
  __shared__ unsigned bc[2];
  __shared__ unsigned ctr, ctr2;
  const int b = blockIdx.x >> 4, e = blockIdx.x & 15;
  const float* sc = scores + (size_t)blockIdx.x * SLEN;
  const int tid = threadIdx.x;
  for (int i = tid; i < SLEN; i += 1024) keys[i] = __float_as_uint(sc[i]);
  if (tid==0){ ctr=0; ctr2=0; }

  unsigned prefix = 0;
  int need = CAP;
  #pragma unroll
  for (int shift = 24; shift >= 0; shift -= 8){
    if (tid < 256) hist[tid] = 0;
    __syncthreads();
    const unsigned maskAbove = (shift==24) ? 0u : (0xFFFFFFFFu << (shift+8));
    for (int i = tid; i < SLEN; i += 1024){
      unsigned k = keys[i];
      if ((k & maskAbove) == prefix) atomicAdd(&hist[(k>>shift)&255u], 1u);
    }
    __syncthreads();
    if (tid == 0){
      unsigned cum = 0; int D = 0;
      for (int d = 255; d >= 0; --d){
        if (cum + hist[d] >= (unsigned)need){ D = d; break; }
        cum += hist[d];
      }
      bc[0] = (unsigned)D; bc[1] = cum;
    }
    __syncthreads();
    need -= (int)bc[1];
    prefix |= bc[0] << shift;
    __syncthreads();
  }

  const unsigned T = prefix;              // exact 32-bit threshold
  const int base = (e*BS + b)*CAP;
  for (int i = tid; i < SLEN; i += 1024){
    unsigned k = keys[i];
    if (k > T){
      unsigned p = atomicAdd(&ctr, 1u);
      float g = __uint_as_float(k);
      int tt = b*SLEN + i;
      tok_idx[base+p] = i;
      gate_raw[base+p] = g;
      atomicAdd(&token_sums[tt], g);
      int hp = atomicAdd(&hit_cnt[tt], 1);
      hit_slot[tt*16 + hp] = base + p;
    } else if (k == T){
      atomicAdd(&ctr2, 1u);
    }
  }
  __syncthreads();
  if ((int)ctr2 == need){
    for (int i = tid; i < SLEN; i += 1024){
      if (keys[i] == T){
        unsigned p = atomicAdd(&ctr, 1u);
        float g = __uint_as_float(T);
        int tt = b*SLEN + i;
        tok_idx[base+p] = i;
        gate_raw[base+p] = g;
        atomicAdd(&token_sums[tt], g);
        int hp = atomicAdd(&hit_cnt[tt], 1);
        hit_slot[tt*16 + hp] = base + p;
      }
    }
  } else if (tid == 0){                   // tie fallback: lowest indices win
    unsigned p = ctr; int rem = need;
    for (int i = 0; i < SLEN && rem > 0; ++i){
      if (keys[i] == T){
        float g = __uint_as_float(T);
        int tt = b*SLEN + i;
        tok_idx[base+p] = i;
        gate_raw[base+p] = g;
        atomicAdd(&token_sums[tt], g);
        int hp = atomicAdd(&hit_cnt[tt], 1);
        hit_slot[tt*16 + hp] = base + p;
        ++p; --rem;
      }
    }
  }
}

// ========== 4-super-phase 256-tile GEMM + T1 XCD swizzle + T5 setprio ==========
// BM=256, virtual BN=256, BK=64, 8 waves (2M x 4N), per-wave C = 128x64.
// G4 8-slot swizzle, pre-swizzled gload source, counted vmcnt(4).
// T5: setprio(1) around each super-phase's MFMA cluster — counted-vmcnt loads
// in flight create wave role-diversity inside the barrier windows.

#define SP_END() \
  __builtin_amdgcn_sched_barrier(0); \
  __builtin_amdgcn_s_barrier();

#define SP_END_VM() \
  __builtin_amdgcn_sched_barrier(0); \
  asm volatile("s_waitcnt vmcnt(4)" ::: "memory"); \
  __builtin_amdgcn_sched_barrier(0); \
  __builtin_amdgcn_s_barrier();

template<int MIB, int NIB>
static __device__ __forceinline__ void mmaQ(f32x4 (&acc)[8][4],
    const s16x8 (&af)[4][2], const s16x8 (&bf)[4][2]){
  #pragma unroll
  for (int i=0;i<4;i++)
    #pragma unroll
    for (int n=0;n<2;n++)
      #pragma unroll
      for (int k=0;k<2;k++)
        acc[MIB+i][NIB+n] = __builtin_amdgcn_mfma_f32_16x16x32_bf16(
            af[i][k], bf[NIB+n][k], acc[MIB+i][NIB+n], 0, 0, 0);
}

template<bool GLU, bool GATHER, bool ROUTED, bool SILU_FIRST, bool COMBINE, int K>
__global__ __launch_bounds__(512) void gemm8_kernel(
    const unsigned short* __restrict__ A,
    const unsigned short* __restrict__ B,
    size_t bstride,
    const int* __restrict__ tok_idx,
    const float* __restrict__ gate_raw,
    const float* __restrict__ token_sums,
    unsigned short* __restrict__ actOut,
    float* __restrict__ fOut,
    const unsigned short* __restrict__ routedIn,
    const int* __restrict__ hit_cnt,
    const int* __restrict__ hit_slot)
{
  constexpr int NT = K/64;
  // ---- T1: XCD-aware bijective block remap (nwg % 8 == 0 for all grids) ----
  const int nwg  = gridDim.x*gridDim.y*gridDim.z;
  const int orig = (blockIdx.z*gridDim.y + blockIdx.y)*gridDim.x + blockIdx.x;
  const int wg   = (orig & 7)*(nwg >> 3) + (orig >> 3);
  const int bxx  = wg % gridDim.x;
  const int byy  = (wg / gridDim.x) % gridDim.y;
  const int bzz  = wg / (gridDim.x * gridDim.y);

  const int e = bzz;
  const int tid = threadIdx.x;
  const int lane = tid & 63, w = tid >> 6;        // 8 waves
  const int wr = w >> 2, wc = w & 3;              // 2M x 4N
  const int lr = lane & 15, lg = lane >> 4;
  const int m0 = byy * 256;
  const int c0 = bxx * (GLU ? 128 : 256);

  __shared__ short Ab[2][16384];   // [buf][256 rows x 64 k] (swizzled storage)
  __shared__ short Bb[2][16384];

  const int srow8 = lane >> 3;
  const int scol  = 8 * ((lane & 7) ^ srow8);
  const unsigned short* pA[2][2];
  const unsigned short* pB[2];
  #pragma unroll
  for (int h = 0; h < 2; ++h){
    #pragma unroll
    for (int j = 0; j < 2; ++j){
      int v = h*128 + w*16 + j*8 + srow8;          // virtual A row 0..255
      long garow;
      if (GLU && GATHER){
        int idx = m0 + v;
        int b = idx >> 9;
        int t = tok_idx[(e*BS + b)*CAP + (idx & (CAP-1))];
        garow = (long)b*SLEN + t;
      } else {
        garow = (ROUTED ? (long)e*TPE : 0L) + m0 + v;
      }
      pA[h][j] = A + (size_t)garow*K + scol;
    }
    int v = h*128 + w*16 + srow8;
    long brow;
    if (GLU) brow = (long)(((v>>4)&1)*INNER + c0 + ((v>>5)*16) + (v & 15));
    else     brow = (long)(c0 + v);
    pB[h] = B + (size_t)e*bstride + (size_t)brow*K + scol;
  }

  auto stageA = [&](int tb, int h){
    short* d = &Ab[tb][h*8192 + w*1024];
    gload16(pA[h][0], d);
    gload16(pA[h][1], d + 512);
    pA[h][0] += 64; pA[h][1] += 64;
  };
  auto stageB = [&](int tb, int h){
    short* d = &Bb[tb][h*8192 + w*1024];
    gload16(pB[h], d);
    gload16(pB[h] + (size_t)8*K, d + 512);
    pB[h] += 64;
  };

  const int swzr  = (lr & 7) * 8;                  // shorts
  const int aRow  = (128*wr + lr)*64;
  const int bRow  = (64*wc + lr)*64;
  const int slot0 = (lg*8) ^ swzr;                 // k=0 slot offset (shorts)

  s16x8 af[4][2], bf[4][2];
  f32x4 acc[8][4];
  #pragma unroll
  for (int i=0;i<8;i++)
    #pragma unroll
    for (int j=0;j<4;j++) acc[i][j] = (f32x4)0.0f;

  auto ldA4 = [&](int tb, int mib){
    #pragma unroll
    for (int i=0;i<4;i++)
      #pragma unroll
      for (int k=0;k<2;k++)
        af[i][k] = *reinterpret_cast<const s16x8*>(&Ab[tb][aRow + (mib+i)*1024 + (slot0 ^ (k*32))]);
  };
  auto ldB2 = [&](int tb, int nib){
    #pragma unroll
    for (int n=0;n<2;n++)
      #pragma unroll
      for (int k=0;k<2;k++)
        bf[nib+n][k] = *reinterpret_cast<const s16x8*>(&Bb[tb][bRow + (nib+n)*1024 + (slot0 ^ (k*32))]);
  };

  // prologue: B(0),A(0) -> buf0; B(1) -> buf1 left in flight
  stageB(0,0); stageB(0,1); stageA(0,0); stageA(0,1); stageB(1,0); stageB(1,1);
  asm volatile("s_waitcnt vmcnt(4)" ::: "memory");
  __builtin_amdgcn_sched_barrier(0);
  __builtin_amdgcn_s_barrier();

  #pragma unroll 1
  for (int it = 0; it < NT/2; ++it){
    ldA4(0,0); ldB2(0,0); ldB2(0,2);
    stageA(1,0); stageA(1,1);
    __builtin_amdgcn_s_setprio(1);
    mmaQ<0,0>(acc, af, bf); mmaQ<0,2>(acc, af, bf);
    __builtin_amdgcn_s_setprio(0);
    SP_END();
    ldA4(0,4);
    stageB(0,0); stageB(0,1);
    __builtin_amdgcn_s_setprio(1);
    mmaQ<4,2>(acc, af, bf); mmaQ<4,0>(acc, af, bf);
    __builtin_amdgcn_s_setprio(0);
    SP_END_VM();
    ldA4(1,0); ldB2(1,0); ldB2(1,2);
    stageA(0,0); stageA(0,1);
    __builtin_amdgcn_s_setprio(1);
    mmaQ<0,0>(acc, af, bf); mmaQ<0,2>(acc, af, bf);
    __builtin_amdgcn_s_setprio(0);
    SP_END();
    ldA4(1,4);
    stageB(1,0); stageB(1,1);
    __builtin_amdgcn_s_setprio(1);
    mmaQ<4,2>(acc, af, bf); mmaQ<4,0>(acc, af, bf);
    __builtin_amdgcn_s_setprio(0);
    SP_END_VM();
  }
  asm volatile("s_waitcnt vmcnt(0)" ::: "memory");

  if (GLU){
    const size_t rowbase = GATHER ? (size_t)e*TPE : (size_t)0;
    #pragma unroll
    for (int mi=0; mi<8; mi++){
      int row = m0 + 128*wr + 16*mi + 4*lg;
      #pragma unroll
      for (int p=0;p<2;p++){
        int col = c0 + 32*wc + 16*p + lr;
        #pragma unroll
        for (int r=0;r<4;r++){
          float g = acc[mi][2*p][r], u = acc[mi][2*p+1][r];
          float a = SILU_FIRST ? (g*sigmoidf_(g))*u : g*(u*sigmoidf_(u));
          actOut[(rowbase + row + r)*(size_t)INNER + col] = f2bf(a);
        }
      }
    }
  } else if (ROUTED){
    // plain bf16 stores of scaled routed output (no atomics)
    #pragma unroll
    for (int mi=0; mi<8; mi++){
      #pragma unroll
      for (int r=0;r<4;r++){
        int slot = m0 + 128*wr + 16*mi + 4*lg + r;     // 0..1023 within expert
        int b = slot >> 9;
        int gs = (e*BS + b)*CAP + (slot & (CAP-1));    // == e*TPE + slot
        int t = tok_idx[gs];
        size_t orow = (size_t)b*SLEN + t;
        float gn = gate_raw[gs] / (token_sums[orow] + 1e-12f);
        #pragma unroll
        for (int ni=0;ni<4;ni++){
          int col = c0 + 64*wc + 16*ni + lr;
          actOut[(size_t)gs*DIM + col] = f2bf(acc[mi][ni][r]*gn);
        }
      }
    }
  } else if (COMBINE){
    #pragma unroll
    for (int mi=0; mi<8; mi++){
      #pragma unroll
      for (int r=0;r<4;r++){
        size_t row = (size_t)(m0 + 128*wr + 16*mi + 4*lg + r);
        int cnt = hit_cnt[row];
        float v0 = acc[mi][0][r], v1 = acc[mi][1][r], v2 = acc[mi][2][r], v3 = acc[mi][3][r];
        int col = c0 + 64*wc + lr;
        for (int h = 0; h < cnt; ++h){
          int gs2 = hit_slot[row*16 + h];
          const unsigned short* rp = routedIn + (size_t)gs2*DIM + col;
          v0 += bf2f(rp[0]); v1 += bf2f(rp[16]); v2 += bf2f(rp[32]); v3 += bf2f(rp[48]);
        }
        fOut[row*DIM + col]      = v0;
        fOut[row*DIM + col + 16] = v1;
        fOut[row*DIM + col + 32] = v2;
        fOut[row*DIM + col + 48] = v3;
      }
    }
  } else {
    #pragma unroll
    for (int mi=0; mi<8; mi++){
      #pragma unroll
      for (int r=0;r<4;r++){
        size_t row = (size_t)(m0 + 128*wr + 16*mi + 4*lg + r);
        #pragma unroll
        for (int ni=0;ni<4;ni++){
          int col = c0 + 64*wc + 16*ni + lr;
          fOut[row*DIM + col] = acc[mi][ni][r];
        }
      }
    }
  }
}

extern "C" void kernel_launch(void* const* d_in, const int* in_sizes, int n_in,
                              void* d_out, int out_size, void* d_ws, size_t ws_size,
                              hipStream_t stream) {
  (void)in_sizes; (void)n_in; (void)out_size; (void)ws_size;
  const float* hidden   = (const float*)d_in[0];
  const float* xu       = (const float*)d_in[1];
  const float* timestep = (const float*)d_in[2];
  const float* gate_w   = (const float*)d_in[3];
  const float* gup      = (const float*)d_in[4];
  const float* dwn      = (const float*)d_in[5];
  const float* shin     = (const float*)d_in[6];
  const float* shout    = (const float*)d_in[7];
  float* out = (float*)d_out;

  char* base = (char*)d_ws;
  size_t off = 0;
  auto alloc = [&](size_t bytes)->char*{
    char* p = base + off; off = (off + bytes + 255) & ~(size_t)255; return p;
  };
  float* token_sums = (float*)alloc((size_t)NTOK*4);
  int*   hit_cnt    = (int*)  alloc((size_t)NTOK*4);
  int*   hit_slot   = (int*)  alloc((size_t)NTOK*16*4);
  float* tpart      = (float*)alloc((size_t)BS*NEXP*4);
  float* scores     = (float*)alloc((size_t)BS*NEXP*SLEN*4);
  int*   tok_idx    = (int*)  alloc((size_t)NEXP*BS*CAP*4);
  float* gate_raw   = (float*)alloc((size_t)NEXP*BS*CAP*4);
  unsigned short* hid_bf   = (unsigned short*)alloc((size_t)NTOK*DIM*2);
  unsigned short* gupT     = (unsigned short*)alloc((size_t)NEXP*2*INNER*DIM*2);
  unsigned short* dwnT     = (unsigned short*)alloc((size_t)NEXP*DIM*INNER*2);
  unsigned short* shinT    = (unsigned short*)alloc((size_t)2*INNER*DIM*2);
  unsigned short* shoutT   = (unsigned short*)alloc((size_t)DIM*INNER*2);
  unsigned short* act_s    = (unsigned short*)alloc((size_t)NTOK*INNER*2);
  unsigned short* act_r    = (unsigned short*)alloc((size_t)NEXP*TPE*INNER*2);
  unsigned short* routed_bf= (unsigned short*)alloc((size_t)NEXP*TPE*DIM*2);
  (void)alloc(1<<16);   // pad

  cast_kernel<<<(NTOK*DIM)/2048, 256, 0, stream>>>(hidden, hid_bf, (long)NTOK*DIM);
  transpose_cast_kernel<<<dim3((2*INNER)/64, DIM/64, NEXP), 256, 0, stream>>>(gup, gupT, DIM, 2*INNER);
  transpose_cast_kernel<<<dim3(DIM/64, INNER/64, NEXP), 256, 0, stream>>>(dwn, dwnT, INNER, DIM);
  transpose_cast_kernel<<<dim3((2*INNER)/64, DIM/64, 1), 256, 0, stream>>>(shin, shinT, DIM, 2*INNER);
  transpose_cast_kernel<<<dim3(DIM/64, INNER/64, 1), 256, 0, stream>>>(shout, shoutT, INNER, DIM);

  tpart_kernel<<<BS*NEXP, 256, 0, stream>>>(timestep, gate_w, tpart);
  router3_kernel<<<NTOK/16, 256, 0, stream>>>(xu, gate_w, tpart, scores, token_sums, hit_cnt);
  topk_kernel<<<BS*NEXP, 1024, 0, stream>>>(scores, tok_idx, gate_raw, token_sums, hit_cnt, hit_slot);

  // gemm1 shared: act_s = h0 * silu(h1)
  gemm8_kernel<true,false,false,false,false,DIM><<<dim3(INNER/128, NTOK/256, 1), 512, 0, stream>>>(
      hid_bf, shinT, 0, nullptr, nullptr, nullptr, act_s, nullptr, nullptr, nullptr, nullptr);
  // gemm1 routed: act_r = silu(g) * u  (gathered rows)
  gemm8_kernel<true,true,false,true,false,DIM><<<dim3(INNER/128, TPE/256, NEXP), 512, 0, stream>>>(
      hid_bf, gupT, (size_t)(2*INNER)*DIM, tok_idx, nullptr, nullptr, act_r, nullptr, nullptr, nullptr, nullptr);
  // gemm2 routed: routed_bf[gs][col] = bf16(acc * gate/(sums+eps))  -- plain stores
  gemm8_kernel<false,false,true,false,false,INNER><<<dim3(DIM/256, TPE/256, NEXP), 512, 0, stream>>>(
      act_r, dwnT, (size_t)DIM*INNER, tok_idx, gate_raw, token_sums, routed_bf, nullptr, nullptr, nullptr, nullptr);
  // gemm2 shared + combine: out = act_s@shoutT + sum of routed hits (writes every element)
  gemm8_kernel<false,false,false,false,true,INNER><<<dim3(DIM/256, NTOK/256, 1), 512, 0, stream>>>(
      act_s, shoutT, 0, nullptr, nullptr, nullptr, nullptr, out, routed_bf, hit_cnt, hit_slot);
}

// Round 15
// 681.198 us; speedup vs baseline: 1.0252x; 1.0252x over previous
//
#include <hip/hip_runtime.h>
#include <hip/hip_bf16.h>
#include <cstdint>
#include <cstddef>

#define BS 2
#define SLEN 4096
#define DIM 2048
#define INNER 1024
#define NEXP 16
#define CAP 512
#define TPE (BS*CAP)      // 1024 tokens per expert
#define NTOK (BS*SLEN)    // 8192

typedef __attribute__((ext_vector_type(4))) float f32x4;
typedef __attribute__((ext_vector_type(8))) short s16x8;

static __device__ __forceinline__ unsigned short f2bf(float f){
  unsigned u = __float_as_uint(f);
  u += 0x7FFFu + ((u >> 16) & 1u);   // RNE
  return (unsigned short)(u >> 16);
}
static __device__ __forceinline__ float bf2f(unsigned short u){
  return __uint_as_float(((unsigned)u) << 16);
}
static __device__ __forceinline__ float sigmoidf_(float x){ return 1.0f/(1.0f+expf(-x)); }

static __device__ __forceinline__ void gload16(const unsigned short* g, short* l){
  __builtin_amdgcn_global_load_lds(
      (const __attribute__((address_space(1))) void*)g,
      (__attribute__((address_space(3))) void*)l, 16, 0, 0);
}

// ---------------- cast fp32 -> bf16 (vectorized) ----------------
__global__ __launch_bounds__(256) void cast_kernel(const float* __restrict__ in,
    unsigned short* __restrict__ out, long n){
  long i = ((long)blockIdx.x*256 + threadIdx.x)*8;
  if (i >= n) return;
  f32x4 a = *reinterpret_cast<const f32x4*>(in+i);
  f32x4 b = *reinterpret_cast<const f32x4*>(in+i+4);
  s16x8 o;
  o[0]=(short)f2bf(a[0]); o[1]=(short)f2bf(a[1]); o[2]=(short)f2bf(a[2]); o[3]=(short)f2bf(a[3]);
  o[4]=(short)f2bf(b[0]); o[5]=(short)f2bf(b[1]); o[6]=(short)f2bf(b[2]); o[7]=(short)f2bf(b[3]);
  *reinterpret_cast<s16x8*>(out+i) = o;
}

// ------------- transpose + cast v2: 64x64 tiles, vectorized both sides -------------
__global__ __launch_bounds__(256) void transpose_cast_kernel(const float* __restrict__ in,
    unsigned short* __restrict__ out, int R, int C){
  __shared__ float t[64][65];
  const size_t mat = blockIdx.z;
  const float* src = in + mat*(size_t)R*C;
  unsigned short* dst = out + mat*(size_t)R*C;
  const int c0 = blockIdx.x*64, r0 = blockIdx.y*64;
  const int tid = threadIdx.x;
  const int tr = tid >> 4, tc4 = (tid & 15)*4;
  #pragma unroll
  for (int i=0;i<4;i++){
    f32x4 v = *reinterpret_cast<const f32x4*>(src + (size_t)(r0+tr+16*i)*C + c0 + tc4);
    t[tr+16*i][tc4+0]=v[0]; t[tr+16*i][tc4+1]=v[1]; t[tr+16*i][tc4+2]=v[2]; t[tr+16*i][tc4+3]=v[3];
  }
  __syncthreads();
  const int sc = tid >> 3, srs = (tid & 7)*8;
  #pragma unroll
  for (int i=0;i<2;i++){
    int cc = sc + 32*i;
    s16x8 o;
    #pragma unroll
    for (int j=0;j<8;j++) o[j] = (short)f2bf(t[srs+j][cc]);
    *reinterpret_cast<s16x8*>(dst + (size_t)(c0+cc)*R + r0 + srs) = o;
  }
}

// ---------------- timestep part of router logits: tpart[b][e] ----------------
__global__ __launch_bounds__(256) void tpart_kernel(const float* __restrict__ timestep,
    const float* __restrict__ gate_w, float* __restrict__ tpart){
  int b = blockIdx.x >> 4, e = blockIdx.x & 15;
  float acc = 0.f;
  for (int d = threadIdx.x; d < DIM; d += 256)
    acc += timestep[b*DIM + d] * gate_w[(size_t)d*NEXP + e];
  #pragma unroll
  for (int o=32;o>0;o>>=1) acc += __shfl_down(acc, o);
  __shared__ float red[4];
  int lane = threadIdx.x & 63, wid = threadIdx.x >> 6;
  if (lane==0) red[wid] = acc;
  __syncthreads();
  if (threadIdx.x==0) tpart[blockIdx.x] = red[0]+red[1]+red[2]+red[3];
}

// ------- router v3: native gate_w[k][e] layout -> one 64B broadcast line per k -------
__global__ __launch_bounds__(256) void router3_kernel(const float* __restrict__ xu,
    const float* __restrict__ gate_w, const float* __restrict__ tpart,
    float* __restrict__ scores, float* __restrict__ token_sums, int* __restrict__ hit_cnt){
  const int tid = threadIdx.x;
  if (tid < 16){
    int tt = blockIdx.x*16 + tid;
    token_sums[tt] = 0.f;
    hit_cnt[tt] = 0;
  }
  const int lane = tid & 63, wv = tid >> 6;
  const int tsub = lane >> 4, e = lane & 15;
  const int tok = blockIdx.x*16 + wv*4 + tsub;
  const int b = tok >> 12, s = tok & (SLEN-1);
  const float* xr  = xu + (size_t)tok*DIM;
  const float* gw2 = gate_w + (size_t)DIM*NEXP + e;   // second-half rows, expert e
  float a0=0.f, a1=0.f;
  #pragma unroll 4
  for (int k = 0; k < DIM; k += 8){
    f32x4 x0 = *reinterpret_cast<const f32x4*>(xr+k);
    f32x4 x1 = *reinterpret_cast<const f32x4*>(xr+k+4);
    a0 += x0[0]*gw2[(size_t)(k+0)*NEXP] + x0[1]*gw2[(size_t)(k+1)*NEXP]
        + x0[2]*gw2[(size_t)(k+2)*NEXP] + x0[3]*gw2[(size_t)(k+3)*NEXP];
    a1 += x1[0]*gw2[(size_t)(k+4)*NEXP] + x1[1]*gw2[(size_t)(k+5)*NEXP]
        + x1[2]*gw2[(size_t)(k+6)*NEXP] + x1[3]*gw2[(size_t)(k+7)*NEXP];
  }
  float v = a0 + a1 + tpart[b*NEXP+e];
  scores[((size_t)(b*NEXP+e))*SLEN + s] = sigmoidf_(v);
}

// ------------- top-512 per (b,e) via exact radix-select + inverse hit index -------------
__global__ __launch_bounds__(1024) void topk_kernel(const float* __restrict__ scores,
    int* __restrict__ tok_idx, float* __restrict__ gate_raw, float* __restrict__ token_sums,
    int* __restrict__ hit_cnt, int* __restrict__ hit_slot){
  __shared__ unsigned keys[SLEN];
  __shared__ unsigned hist[256];
  __shared__ unsigned bc[2];
  __shared__ unsigned ctr, ctr2;
  const int b = blockIdx.x >> 4, e = blockIdx.x & 15;
  const float* sc = scores + (size_t)blockIdx.x * SLEN;
  const int tid = threadIdx.x;
  for (int i = tid; i < SLEN; i += 1024) keys[i] = __float_as_uint(sc[i]);
  if (tid==0){ ctr=0; ctr2=0; }

  unsigned prefix = 0;
  int need = CAP;
  #pragma unroll
  for (int shift = 24; shift >= 0; shift -= 8){
    if (tid < 256) hist[tid] = 0;
    __syncthreads();
    const unsigned maskAbove = (shift==24) ? 0u : (0xFFFFFFFFu << (shift+8));
    for (int i = tid; i < SLEN; i += 1024){
      unsigned k = keys[i];
      if ((k & maskAbove) == prefix) atomicAdd(&hist[(k>>shift)&255u], 1u);
    }
    __syncthreads();
    if (tid == 0){
      unsigned cum = 0; int D = 0;
      for (int d = 255; d >= 0; --d){
        if (cum + hist[d] >= (unsigned)need){ D = d; break; }
        cum += hist[d];
      }
      bc[0] = (unsigned)D; bc[1] = cum;
    }
    __syncthreads();
    need -= (int)bc[1];
    prefix |= bc[0] << shift;
    __syncthreads();
  }

  const unsigned T = prefix;              // exact 32-bit threshold
  const int base = (e*BS + b)*CAP;
  for (int i = tid; i < SLEN; i += 1024){
    unsigned k = keys[i];
    if (k > T){
      unsigned p = atomicAdd(&ctr, 1u);
      float g = __uint_as_float(k);
      int tt = b*SLEN + i;
      tok_idx[base+p] = i;
      gate_raw[base+p] = g;
      atomicAdd(&token_sums[tt], g);
      int hp = atomicAdd(&hit_cnt[tt], 1);
      hit_slot[tt*16 + hp] = base + p;
    } else if (k == T){
      atomicAdd(&ctr2, 1u);
    }
  }
  __syncthreads();
  if ((int)ctr2 == need){
    for (int i = tid; i < SLEN; i += 1024){
      if (keys[i] == T){
        unsigned p = atomicAdd(&ctr, 1u);
        float g = __uint_as_float(T);
        int tt = b*SLEN + i;
        tok_idx[base+p] = i;
        gate_raw[base+p] = g;
        atomicAdd(&token_sums[tt], g);
        int hp = atomicAdd(&hit_cnt[tt], 1);
        hit_slot[tt*16 + hp] = base + p;
      }
    }
  } else if (tid == 0){                   // tie fallback: lowest indices win
    unsigned p = ctr; int rem = need;
    for (int i = 0; i < SLEN && rem > 0; ++i){
      if (keys[i] == T){
        float g = __uint_as_float(T);
        int tt = b*SLEN + i;
        tok_idx[base+p] = i;
        gate_raw[base+p] = g;
        atomicAdd(&token_sums[tt], g);
        int hp = atomicAdd(&hit_cnt[tt], 1);
        hit_slot[tt*16 + hp] = base + p;
        ++p; --rem;
      }
    }
  }
}

// ========== 4-super-phase 256-tile GEMM + T1 XCD swizzle (r13 config, best) ==========
// BM=256, virtual BN=256, BK=64, 8 waves (2M x 4N), per-wave C = 128x64.
// G4 8-slot swizzle, pre-swizzled gload source, counted vmcnt(4).
// T5 setprio REMOVED: measured -13 us (r14) — barrier-lockstep waves have no
// role split for the scheduler to arbitrate (m190 regime).

#define SP_END() \
  __builtin_amdgcn_sched_barrier(0); \
  __builtin_amdgcn_s_barrier();

#define SP_END_VM() \
  __builtin_amdgcn_sched_barrier(0); \
  asm volatile("s_waitcnt vmcnt(4)" ::: "memory"); \
  __builtin_amdgcn_sched_barrier(0); \
  __builtin_amdgcn_s_barrier();

template<int MIB, int NIB>
static __device__ __forceinline__ void mmaQ(f32x4 (&acc)[8][4],
    const s16x8 (&af)[4][2], const s16x8 (&bf)[4][2]){
  #pragma unroll
  for (int i=0;i<4;i++)
    #pragma unroll
    for (int n=0;n<2;n++)
      #pragma unroll
      for (int k=0;k<2;k++)
        acc[MIB+i][NIB+n] = __builtin_amdgcn_mfma_f32_16x16x32_bf16(
            af[i][k], bf[NIB+n][k], acc[MIB+i][NIB+n], 0, 0, 0);
}

template<bool GLU, bool GATHER, bool ROUTED, bool SILU_FIRST, bool COMBINE, int K>
__global__ __launch_bounds__(512) void gemm8_kernel(
    const unsigned short* __restrict__ A,
    const unsigned short* __restrict__ B,
    size_t bstride,
    const int* __restrict__ tok_idx,
    const float* __restrict__ gate_raw,
    const float* __restrict__ token_sums,
    unsigned short* __restrict__ actOut,
    float* __restrict__ fOut,
    const unsigned short* __restrict__ routedIn,
    const int* __restrict__ hit_cnt,
    const int* __restrict__ hit_slot)
{
  constexpr int NT = K/64;
  // ---- T1: XCD-aware bijective block remap (nwg % 8 == 0 for all grids) ----
  const int nwg  = gridDim.x*gridDim.y*gridDim.z;
  const int orig = (blockIdx.z*gridDim.y + blockIdx.y)*gridDim.x + blockIdx.x;
  const int wg   = (orig & 7)*(nwg >> 3) + (orig >> 3);
  const int bxx  = wg % gridDim.x;
  const int byy  = (wg / gridDim.x) % gridDim.y;
  const int bzz  = wg / (gridDim.x * gridDim.y);

  const int e = bzz;
  const int tid = threadIdx.x;
  const int lane = tid & 63, w = tid >> 6;        // 8 waves
  const int wr = w >> 2, wc = w & 3;              // 2M x 4N
  const int lr = lane & 15, lg = lane >> 4;
  const int m0 = byy * 256;
  const int c0 = bxx * (GLU ? 128 : 256);

  __shared__ short Ab[2][16384];   // [buf][256 rows x 64 k] (swizzled storage)
  __shared__ short Bb[2][16384];

  const int srow8 = lane >> 3;
  const int scol  = 8 * ((lane & 7) ^ srow8);
  const unsigned short* pA[2][2];
  const unsigned short* pB[2];
  #pragma unroll
  for (int h = 0; h < 2; ++h){
    #pragma unroll
    for (int j = 0; j < 2; ++j){
      int v = h*128 + w*16 + j*8 + srow8;          // virtual A row 0..255
      long garow;
      if (GLU && GATHER){
        int idx = m0 + v;
        int b = idx >> 9;
        int t = tok_idx[(e*BS + b)*CAP + (idx & (CAP-1))];
        garow = (long)b*SLEN + t;
      } else {
        garow = (ROUTED ? (long)e*TPE : 0L) + m0 + v;
      }
      pA[h][j] = A + (size_t)garow*K + scol;
    }
    int v = h*128 + w*16 + srow8;
    long brow;
    if (GLU) brow = (long)(((v>>4)&1)*INNER + c0 + ((v>>5)*16) + (v & 15));
    else     brow = (long)(c0 + v);
    pB[h] = B + (size_t)e*bstride + (size_t)brow*K + scol;
  }

  auto stageA = [&](int tb, int h){
    short* d = &Ab[tb][h*8192 + w*1024];
    gload16(pA[h][0], d);
    gload16(pA[h][1], d + 512);
    pA[h][0] += 64; pA[h][1] += 64;
  };
  auto stageB = [&](int tb, int h){
    short* d = &Bb[tb][h*8192 + w*1024];
    gload16(pB[h], d);
    gload16(pB[h] + (size_t)8*K, d + 512);
    pB[h] += 64;
  };

  const int swzr  = (lr & 7) * 8;                  // shorts
  const int aRow  = (128*wr + lr)*64;
  const int bRow  = (64*wc + lr)*64;
  const int slot0 = (lg*8) ^ swzr;                 // k=0 slot offset (shorts)

  s16x8 af[4][2], bf[4][2];
  f32x4 acc[8][4];
  #pragma unroll
  for (int i=0;i<8;i++)
    #pragma unroll
    for (int j=0;j<4;j++) acc[i][j] = (f32x4)0.0f;

  auto ldA4 = [&](int tb, int mib){
    #pragma unroll
    for (int i=0;i<4;i++)
      #pragma unroll
      for (int k=0;k<2;k++)
        af[i][k] = *reinterpret_cast<const s16x8*>(&Ab[tb][aRow + (mib+i)*1024 + (slot0 ^ (k*32))]);
  };
  auto ldB2 = [&](int tb, int nib){
    #pragma unroll
    for (int n=0;n<2;n++)
      #pragma unroll
      for (int k=0;k<2;k++)
        bf[nib+n][k] = *reinterpret_cast<const s16x8*>(&Bb[tb][bRow + (nib+n)*1024 + (slot0 ^ (k*32))]);
  };

  // prologue: B(0),A(0) -> buf0; B(1) -> buf1 left in flight
  stageB(0,0); stageB(0,1); stageA(0,0); stageA(0,1); stageB(1,0); stageB(1,1);
  asm volatile("s_waitcnt vmcnt(4)" ::: "memory");
  __builtin_amdgcn_sched_barrier(0);
  __builtin_amdgcn_s_barrier();

  #pragma unroll 1
  for (int it = 0; it < NT/2; ++it){
    ldA4(0,0); ldB2(0,0); ldB2(0,2);
    stageA(1,0); stageA(1,1);
    mmaQ<0,0>(acc, af, bf); mmaQ<0,2>(acc, af, bf);
    SP_END();
    ldA4(0,4);
    stageB(0,0); stageB(0,1);
    mmaQ<4,2>(acc, af, bf); mmaQ<4,0>(acc, af, bf);
    SP_END_VM();
    ldA4(1,0); ldB2(1,0); ldB2(1,2);
    stageA(0,0); stageA(0,1);
    mmaQ<0,0>(acc, af, bf); mmaQ<0,2>(acc, af, bf);
    SP_END();
    ldA4(1,4);
    stageB(1,0); stageB(1,1);
    mmaQ<4,2>(acc, af, bf); mmaQ<4,0>(acc, af, bf);
    SP_END_VM();
  }
  asm volatile("s_waitcnt vmcnt(0)" ::: "memory");

  if (GLU){
    const size_t rowbase = GATHER ? (size_t)e*TPE : (size_t)0;
    #pragma unroll
    for (int mi=0; mi<8; mi++){
      int row = m0 + 128*wr + 16*mi + 4*lg;
      #pragma unroll
      for (int p=0;p<2;p++){
        int col = c0 + 32*wc + 16*p + lr;
        #pragma unroll
        for (int r=0;r<4;r++){
          float g = acc[mi][2*p][r], u = acc[mi][2*p+1][r];
          float a = SILU_FIRST ? (g*sigmoidf_(g))*u : g*(u*sigmoidf_(u));
          actOut[(rowbase + row + r)*(size_t)INNER + col] = f2bf(a);
        }
      }
    }
  } else if (ROUTED){
    // plain bf16 stores of scaled routed output (no atomics)
    #pragma unroll
    for (int mi=0; mi<8; mi++){
      #pragma unroll
      for (int r=0;r<4;r++){
        int slot = m0 + 128*wr + 16*mi + 4*lg + r;     // 0..1023 within expert
        int b = slot >> 9;
        int gs = (e*BS + b)*CAP + (slot & (CAP-1));    // == e*TPE + slot
        int t = tok_idx[gs];
        size_t orow = (size_t)b*SLEN + t;
        float gn = gate_raw[gs] / (token_sums[orow] + 1e-12f);
        #pragma unroll
        for (int ni=0;ni<4;ni++){
          int col = c0 + 64*wc + 16*ni + lr;
          actOut[(size_t)gs*DIM + col] = f2bf(acc[mi][ni][r]*gn);
        }
      }
    }
  } else if (COMBINE){
    #pragma unroll
    for (int mi=0; mi<8; mi++){
      #pragma unroll
      for (int r=0;r<4;r++){
        size_t row = (size_t)(m0 + 128*wr + 16*mi + 4*lg + r);
        int cnt = hit_cnt[row];
        float v0 = acc[mi][0][r], v1 = acc[mi][1][r], v2 = acc[mi][2][r], v3 = acc[mi][3][r];
        int col = c0 + 64*wc + lr;
        for (int h = 0; h < cnt; ++h){
          int gs2 = hit_slot[row*16 + h];
          const unsigned short* rp = routedIn + (size_t)gs2*DIM + col;
          v0 += bf2f(rp[0]); v1 += bf2f(rp[16]); v2 += bf2f(rp[32]); v3 += bf2f(rp[48]);
        }
        fOut[row*DIM + col]      = v0;
        fOut[row*DIM + col + 16] = v1;
        fOut[row*DIM + col + 32] = v2;
        fOut[row*DIM + col + 48] = v3;
      }
    }
  } else {
    #pragma unroll
    for (int mi=0; mi<8; mi++){
      #pragma unroll
      for (int r=0;r<4;r++){
        size_t row = (size_t)(m0 + 128*wr + 16*mi + 4*lg + r);
        #pragma unroll
        for (int ni=0;ni<4;ni++){
          int col = c0 + 64*wc + 16*ni + lr;
          fOut[row*DIM + col] = acc[mi][ni][r];
        }
      }
    }
  }
}

extern "C" void kernel_launch(void* const* d_in, const int* in_sizes, int n_in,
                              void* d_out, int out_size, void* d_ws, size_t ws_size,
                              hipStream_t stream) {
  (void)in_sizes; (void)n_in; (void)out_size; (void)ws_size;
  const float* hidden   = (const float*)d_in[0];
  const float* xu       = (const float*)d_in[1];
  const float* timestep = (const float*)d_in[2];
  const float* gate_w   = (const float*)d_in[3];
  const float* gup      = (const float*)d_in[4];
  const float* dwn      = (const float*)d_in[5];
  const float* shin     = (const float*)d_in[6];
  const float* shout    = (const float*)d_in[7];
  float* out = (float*)d_out;

  char* base = (char*)d_ws;
  size_t off = 0;
  auto alloc = [&](size_t bytes)->char*{
    char* p = base + off; off = (off + bytes + 255) & ~(size_t)255; return p;
  };
  float* token_sums = (float*)alloc((size_t)NTOK*4);
  int*   hit_cnt    = (int*)  alloc((size_t)NTOK*4);
  int*   hit_slot   = (int*)  alloc((size_t)NTOK*16*4);
  float* tpart      = (float*)alloc((size_t)BS*NEXP*4);
  float* scores     = (float*)alloc((size_t)BS*NEXP*SLEN*4);
  int*   tok_idx    = (int*)  alloc((size_t)NEXP*BS*CAP*4);
  float* gate_raw   = (float*)alloc((size_t)NEXP*BS*CAP*4);
  unsigned short* hid_bf   = (unsigned short*)alloc((size_t)NTOK*DIM*2);
  unsigned short* gupT     = (unsigned short*)alloc((size_t)NEXP*2*INNER*DIM*2);
  unsigned short* dwnT     = (unsigned short*)alloc((size_t)NEXP*DIM*INNER*2);
  unsigned short* shinT    = (unsigned short*)alloc((size_t)2*INNER*DIM*2);
  unsigned short* shoutT   = (unsigned short*)alloc((size_t)DIM*INNER*2);
  unsigned short* act_s    = (unsigned short*)alloc((size_t)NTOK*INNER*2);
  unsigned short* act_r    = (unsigned short*)alloc((size_t)NEXP*TPE*INNER*2);
  unsigned short* routed_bf= (unsigned short*)alloc((size_t)NEXP*TPE*DIM*2);
  (void)alloc(1<<16);   // pad

  cast_kernel<<<(NTOK*DIM)/2048, 256, 0, stream>>>(hidden, hid_bf, (long)NTOK*DIM);
  transpose_cast_kernel<<<dim3((2*INNER)/64, DIM/64, NEXP), 256, 0, stream>>>(gup, gupT, DIM, 2*INNER);
  transpose_cast_kernel<<<dim3(DIM/64, INNER/64, NEXP), 256, 0, stream>>>(dwn, dwnT, INNER, DIM);
  transpose_cast_kernel<<<dim3((2*INNER)/64, DIM/64, 1), 256, 0, stream>>>(shin, shinT, DIM, 2*INNER);
  transpose_cast_kernel<<<dim3(DIM/64, INNER/64, 1), 256, 0, stream>>>(shout, shoutT, INNER, DIM);

  tpart_kernel<<<BS*NEXP, 256, 0, stream>>>(timestep, gate_w, tpart);
  router3_kernel<<<NTOK/16, 256, 0, stream>>>(xu, gate_w, tpart, scores, token_sums, hit_cnt);
  topk_kernel<<<BS*NEXP, 1024, 0, stream>>>(scores, tok_idx, gate_raw, token_sums, hit_cnt, hit_slot);

  // gemm1 shared: act_s = h0 * silu(h1)
  gemm8_kernel<true,false,false,false,false,DIM><<<dim3(INNER/128, NTOK/256, 1), 512, 0, stream>>>(
      hid_bf, shinT, 0, nullptr, nullptr, nullptr, act_s, nullptr, nullptr, nullptr, nullptr);
  // gemm1 routed: act_r = silu(g) * u  (gathered rows)
  gemm8_kernel<true,true,false,true,false,DIM><<<dim3(INNER/128, TPE/256, NEXP), 512, 0, stream>>>(
      hid_bf, gupT, (size_t)(2*INNER)*DIM, tok_idx, nullptr, nullptr, act_r, nullptr, nullptr, nullptr, nullptr);
  // gemm2 routed: routed_bf[gs][col] = bf16(acc * gate/(sums+eps))  -- plain stores
  gemm8_kernel<false,false,true,false,false,INNER><<<dim3(DIM/256, TPE/256, NEXP), 512, 0, stream>>>(
      act_r, dwnT, (size_t)DIM*INNER, tok_idx, gate_raw, token_sums, routed_bf, nullptr, nullptr, nullptr, nullptr);
  // gemm2 shared + combine: out = act_s@shoutT + sum of routed hits (writes every element)
  gemm8_kernel<false,false,false,false,true,INNER><<<dim3(DIM/256, NTOK/256, 1), 512, 0, stream>>>(
      act_s, shoutT, 0, nullptr, nullptr, nullptr, nullptr, out, routed_bf, hit_cnt, hit_slot);
}